// Round 2
// baseline (1985.441 us; speedup 1.0000x reference)
//
#include <hip/hip_runtime.h>
#include <cstdint>

typedef _Float16 f16;
typedef _Float16 f16x8 __attribute__((ext_vector_type(8)));
typedef _Float16 f16x4 __attribute__((ext_vector_type(4)));
typedef float    f32x4 __attribute__((ext_vector_type(4)));

#define DIMN 1024
#define BATCH 32768
#define NLAYERS 18
#define NBLOCKS 6

// ---- async global->LDS, 16B per lane ----
__device__ __forceinline__ void gl2lds16(const f16* g, const f16* l) {
    auto gp = (const __attribute__((address_space(1))) unsigned int*)(uintptr_t)g;
    auto lp = (__attribute__((address_space(3))) unsigned int*)(uintptr_t)l;
    __builtin_amdgcn_global_load_lds(gp, lp, 16, 0, 0);
}

// ---- convert fp32 x -> fp16 ----
__global__ void cvt_kernel(const float* __restrict__ x, f16* __restrict__ o) {
    int i = (blockIdx.x * 256 + threadIdx.x) * 4;
    float4 v = *(const float4*)&x[i];
    f16x4 r;
    r[0] = (f16)v.x; r[1] = (f16)v.y; r[2] = (f16)v.z; r[3] = (f16)v.w;
    *(f16x4*)&o[i] = r;
}

// ---- W_eff = dequant(int4, group-16 scales) + lb@la, fp16 output ----
// grid: 18*1024 blocks (one per layer-row), 256 threads; thread does 4 cols
__global__ void prep_w_kernel(const int* __restrict__ qw,
                              const float* __restrict__ sc,
                              const float* __restrict__ la,
                              const float* __restrict__ lb,
                              f16* __restrict__ W) {
    int b = blockIdx.x;
    int li = b >> 10, o = b & 1023;
    __shared__ float lbs[32];
    int tid = threadIdx.x;
    if (tid < 32) lbs[tid] = lb[((size_t)li * 1024 + o) * 32 + tid];
    __syncthreads();
    int i0 = tid * 4;
    size_t rowbase = ((size_t)li * 1024 + o) * 1024;
    int4 code = *(const int4*)&qw[rowbase + i0];
    float scale = sc[((size_t)li * 1024 + o) * 64 + (i0 >> 4)];
    const float* laL = la + (size_t)li * 32 * 1024;
    float a0 = 0.f, a1 = 0.f, a2 = 0.f, a3 = 0.f;
#pragma unroll
    for (int r = 0; r < 32; ++r) {
        float4 lav = *(const float4*)&laL[r * 1024 + i0];
        float lbv = lbs[r];
        a0 += lbv * lav.x; a1 += lbv * lav.y; a2 += lbv * lav.z; a3 += lbv * lav.w;
    }
    f16x4 out;
    out[0] = (f16)((float)code.x * scale + a0);
    out[1] = (f16)((float)code.y * scale + a1);
    out[2] = (f16)((float)code.z * scale + a2);
    out[3] = (f16)((float)code.w * scale + a3);
    *(f16x4*)&W[rowbase + i0] = out;
}

// ---- main GEMM: C[M,1024] = A[M,1024] @ W^T + bias, optional relu, fp16 out ----
// BM=BN=128, BK=32, 256 threads (4 waves, 2x2), wave does 4x4 16x16x32 MFMAs
__global__ __launch_bounds__(256, 2) void gemm_kernel(
        const f16* __restrict__ A, const f16* __restrict__ W,
        const float* __restrict__ bias, f16* __restrict__ C, int relu) {
    __shared__ __align__(16) f16 As[128 * 32];
    __shared__ __align__(16) f16 Bs[128 * 32];

    int tid = threadIdx.x;
    int l = tid & 63, w = tid >> 6;
    int wm = w & 1, wn = w >> 1;

    // XCD swizzle: all 8 n-tiles of an m-tile on same XCD (A-tile L2 reuse)
    int bid = blockIdx.x;
    int mg = bid >> 6;
    int inner = bid & 63;
    int mt = (mg << 3) | (inner & 7);
    int nt = (inner >> 3) & 7;
    int bm = mt * 128, bn = nt * 128;

    // staging chunk ids: chunk = 8 f16 of a row
    int row0 = tid >> 2, kc0 = tid & 3;
    const f16* a0 = A + (size_t)(bm + row0) * DIMN + kc0 * 8;
    const f16* a1 = a0 + (size_t)64 * DIMN;
    const f16* b0 = W + (size_t)(bn + row0) * DIMN + kc0 * 8;
    const f16* b1 = b0 + (size_t)64 * DIMN;
    f16* lA0 = As + w * 512;
    f16* lA1 = As + 2048 + w * 512;
    f16* lB0 = Bs + w * 512;
    f16* lB1 = Bs + 2048 + w * 512;

    f32x4 acc[4][4] = {};

    int mrow = wm * 64 + (l & 15);
    int nrow = wn * 64 + (l & 15);
    int q8 = (l >> 4) * 8;

    for (int kt = 0; kt < DIMN; kt += 32) {
        gl2lds16(a0 + kt, lA0);
        gl2lds16(a1 + kt, lA1);
        gl2lds16(b0 + kt, lB0);
        gl2lds16(b1 + kt, lB1);
        asm volatile("s_waitcnt vmcnt(0)" ::: "memory");
        __syncthreads();

        f16x8 af[4], bfr[4];
#pragma unroll
        for (int i = 0; i < 4; ++i) {
            af[i]  = *(const f16x8*)&As[(mrow + i * 16) * 32 + q8];
            bfr[i] = *(const f16x8*)&Bs[(nrow + i * 16) * 32 + q8];
        }
#pragma unroll
        for (int i = 0; i < 4; ++i)
#pragma unroll
            for (int j = 0; j < 4; ++j)
                acc[i][j] = __builtin_amdgcn_mfma_f32_16x16x32_f16(
                    af[i], bfr[j], acc[i][j], 0, 0, 0);
        __syncthreads();
    }

    // epilogue: C/D layout row=(lane>>4)*4+reg, col=lane&15 (m89-verified)
    int col0 = bn + wn * 64 + (l & 15);
    int rbase = bm + wm * 64 + (l >> 4) * 4;
    float bsv[4];
#pragma unroll
    for (int j = 0; j < 4; ++j) bsv[j] = bias[col0 + j * 16];
#pragma unroll
    for (int i = 0; i < 4; ++i) {
#pragma unroll
        for (int j = 0; j < 4; ++j) {
#pragma unroll
            for (int r = 0; r < 4; ++r) {
                float v = acc[i][j][r] + bsv[j];
                if (relu) v = fmaxf(v, 0.f);
                C[(size_t)(rbase + i * 16 + r) * DIMN + (col0 + j * 16)] = (f16)v;
            }
        }
    }
}

// ---- residual + layernorm (mode 0) or final residual fp32 out (mode 1) ----
// grid: 32768 rows, 256 threads; thread handles 4 consecutive cols
__global__ void res_ln_kernel(const f16* __restrict__ y, f16* __restrict__ h,
                              const float* __restrict__ g, const float* __restrict__ b,
                              float* __restrict__ outF, int mode) {
    int row = blockIdx.x;
    int tid = threadIdx.x;
    int c0 = tid * 4;
    const f16* yr = y + (size_t)row * DIMN;
    f16* hr = h + (size_t)row * DIMN;

    f16x4 yv = *(const f16x4*)&yr[c0];
    f16x4 hv = *(const f16x4*)&hr[c0];
    float v[4];
    float s = 0.f, sq = 0.f;
#pragma unroll
    for (int i = 0; i < 4; ++i) {
        v[i] = (float)yv[i] + (float)hv[i];
        s += v[i]; sq += v[i] * v[i];
    }
#pragma unroll
    for (int o = 32; o > 0; o >>= 1) {
        s += __shfl_xor(s, o);
        sq += __shfl_xor(sq, o);
    }
    __shared__ float red[8];
    int wv = tid >> 6, ln = tid & 63;
    if (ln == 0) { red[wv] = s; red[4 + wv] = sq; }
    __syncthreads();
    float S1 = red[0] + red[1] + red[2] + red[3];
    float S2 = red[4] + red[5] + red[6] + red[7];
    float mu = S1 * (1.f / 1024.f);
    float var = S2 * (1.f / 1024.f) - mu * mu;
    float rs = rsqrtf(var + 1e-5f);

    if (mode == 0) {
        float4 gv = *(const float4*)&g[c0];
        float4 bv = *(const float4*)&b[c0];
        f16x4 outv;
        outv[0] = (f16)((v[0] - mu) * rs * gv.x + bv.x);
        outv[1] = (f16)((v[1] - mu) * rs * gv.y + bv.y);
        outv[2] = (f16)((v[2] - mu) * rs * gv.z + bv.z);
        outv[3] = (f16)((v[3] - mu) * rs * gv.w + bv.w);
        *(f16x4*)&hr[c0] = outv;
    } else {
        float4 ov;
        ov.x = v[0]; ov.y = v[1]; ov.z = v[2]; ov.w = v[3];
        *(float4*)&outF[(size_t)row * DIMN + c0] = ov;
    }
}

extern "C" void kernel_launch(void* const* d_in, const int* in_sizes, int n_in,
                              void* d_out, int out_size, void* d_ws, size_t ws_size,
                              hipStream_t stream) {
    const float* x    = (const float*)d_in[0];
    const int*   qw   = (const int*)d_in[1];
    const float* sc   = (const float*)d_in[2];
    const float* bias = (const float*)d_in[3];
    const float* la   = (const float*)d_in[4];
    const float* lb   = (const float*)d_in[5];
    const float* lng  = (const float*)d_in[6];
    const float* lnb  = (const float*)d_in[7];
    float* out = (float*)d_out;

    char* ws = (char*)d_ws;
    f16* Weff = (f16*)ws;                                   // 37,748,736 B
    f16* H    = (f16*)(ws + (size_t)37748736);              // 67,108,864 B
    f16* P    = (f16*)(ws + (size_t)37748736 + 67108864);   // 67,108,864 B
    f16* Q    = (f16*)d_out;                                // scratch alias (dead before final fp32 write)

    cvt_kernel<<<BATCH * DIMN / (256 * 4), 256, 0, stream>>>(x, H);
    prep_w_kernel<<<NLAYERS * 1024, 256, 0, stream>>>(qw, sc, la, lb, Weff);

    for (int blk = 0; blk < NBLOCKS; ++blk) {
        for (int j = 0; j < 3; ++j) {
            int li = blk * 3 + j;
            const f16* in = (j == 0) ? H : ((j == 1) ? P : Q);
            f16* o = (j == 1) ? Q : P;
            gemm_kernel<<<2048, 256, 0, stream>>>(
                in, Weff + ((size_t)li << 20), bias + li * 1024, o, (j < 2) ? 1 : 0);
        }
        int lnidx = (blk < 5) ? blk : 4;  // unused in mode 1
        res_ln_kernel<<<BATCH, 256, 0, stream>>>(
            P, H, lng + lnidx * 1024, lnb + lnidx * 1024, out, (blk == 5) ? 1 : 0);
    }
}

// Round 3
// 1946.016 us; speedup vs baseline: 1.0203x; 1.0203x over previous
//
#include <hip/hip_runtime.h>
#include <cstdint>

typedef _Float16 f16;
typedef _Float16 f16x8 __attribute__((ext_vector_type(8)));
typedef _Float16 f16x4 __attribute__((ext_vector_type(4)));
typedef float    f32x4 __attribute__((ext_vector_type(4)));

#define DIMN 1024
#define BATCH 32768
#define NLAYERS 18
#define NBLOCKS 6

// ---- async global->LDS, 16B per lane ----
__device__ __forceinline__ void gl2lds16(const f16* g, const f16* l) {
    auto gp = (const __attribute__((address_space(1))) unsigned int*)(uintptr_t)g;
    auto lp = (__attribute__((address_space(3))) unsigned int*)(uintptr_t)l;
    __builtin_amdgcn_global_load_lds(gp, lp, 16, 0, 0);
}

// ---- convert fp32 x -> fp16 ----
__global__ void cvt_kernel(const float* __restrict__ x, f16* __restrict__ o) {
    int i = (blockIdx.x * 256 + threadIdx.x) * 4;
    float4 v = *(const float4*)&x[i];
    f16x4 r;
    r[0] = (f16)v.x; r[1] = (f16)v.y; r[2] = (f16)v.z; r[3] = (f16)v.w;
    *(f16x4*)&o[i] = r;
}

// ---- W_eff = dequant(int4, group-16 scales) + lb@la, fp16 output ----
// grid: 18*128 blocks (8 output rows per block -> la loads amortized 8x)
__global__ __launch_bounds__(256) void prep_w_kernel(
        const int* __restrict__ qw, const float* __restrict__ sc,
        const float* __restrict__ la, const float* __restrict__ lb,
        f16* __restrict__ W) {
    int b = blockIdx.x;
    int li = b >> 7;
    int og = (b & 127) << 3;  // first of 8 rows
    __shared__ float lbs[8][32];
    int tid = threadIdx.x;
    lbs[tid >> 5][tid & 31] = lb[((size_t)li * 1024 + og + (tid >> 5)) * 32 + (tid & 31)];
    __syncthreads();

    int i0 = tid * 4;  // 4 cols per thread
    const float* laL = la + (size_t)li * 32 * 1024;
    float acc[8][4] = {};
    for (int r = 0; r < 32; ++r) {
        float4 lav = *(const float4*)&laL[r * 1024 + i0];
#pragma unroll
        for (int q = 0; q < 8; ++q) {
            float wv = lbs[q][r];
            acc[q][0] += wv * lav.x; acc[q][1] += wv * lav.y;
            acc[q][2] += wv * lav.z; acc[q][3] += wv * lav.w;
        }
    }
#pragma unroll
    for (int q = 0; q < 8; ++q) {
        size_t row = (size_t)li * 1024 + og + q;
        size_t rowbase = row * 1024;
        int4 code = *(const int4*)&qw[rowbase + i0];
        float scale = sc[row * 64 + (i0 >> 4)];
        f16x4 o;
        o[0] = (f16)((float)code.x * scale + acc[q][0]);
        o[1] = (f16)((float)code.y * scale + acc[q][1]);
        o[2] = (f16)((float)code.z * scale + acc[q][2]);
        o[3] = (f16)((float)code.w * scale + acc[q][3]);
        *(f16x4*)&W[rowbase + i0] = o;
    }
}

// ---- main GEMM: C[M,1024] = A[M,1024] @ W^T + bias, optional relu, fp16 out ----
// BM=BN=128, BK=32, 256 threads (4 waves, 2x2), wave does 4x4 16x16x32 MFMAs
#define LDC 136  // padded f16 stride for epilogue repack
__global__ __launch_bounds__(256, 3) void gemm_kernel(
        const f16* __restrict__ A, const f16* __restrict__ W,
        const float* __restrict__ bias, f16* __restrict__ C, int relu) {
    __shared__ __align__(16) char smem[128 * LDC * 2];  // 34816 B; As/Bs union with Cs
    f16* As = (f16*)smem;
    f16* Bs = (f16*)(smem + 8192);
    f16* Cs = (f16*)smem;

    int tid = threadIdx.x;
    int l = tid & 63, w = tid >> 6;
    int wm = w & 1, wn = w >> 1;

    // XCD swizzle: all 8 n-tiles of an m-tile on same XCD (A-tile L2 reuse)
    int bid = blockIdx.x;
    int mg = bid >> 6;
    int inner = bid & 63;
    int mt = (mg << 3) | (inner & 7);
    int nt = (inner >> 3) & 7;
    int bm = mt * 128, bn = nt * 128;

    int row0 = tid >> 2, kc0 = tid & 3;
    const f16* a0 = A + (size_t)(bm + row0) * DIMN + kc0 * 8;
    const f16* a1 = a0 + (size_t)64 * DIMN;
    const f16* b0 = W + (size_t)(bn + row0) * DIMN + kc0 * 8;
    const f16* b1 = b0 + (size_t)64 * DIMN;
    f16* lA0 = As + w * 512;
    f16* lA1 = As + 2048 + w * 512;
    f16* lB0 = Bs + w * 512;
    f16* lB1 = Bs + 2048 + w * 512;

    f32x4 acc[4][4] = {};

    int mrow = wm * 64 + (l & 15);
    int nrow = wn * 64 + (l & 15);
    int q8 = (l >> 4) * 8;

    for (int kt = 0; kt < DIMN; kt += 32) {
        gl2lds16(a0 + kt, lA0);
        gl2lds16(a1 + kt, lA1);
        gl2lds16(b0 + kt, lB0);
        gl2lds16(b1 + kt, lB1);
        asm volatile("s_waitcnt vmcnt(0)" ::: "memory");
        __syncthreads();

        f16x8 af[4], bfr[4];
#pragma unroll
        for (int i = 0; i < 4; ++i) {
            af[i]  = *(const f16x8*)&As[(mrow + i * 16) * 32 + q8];
            bfr[i] = *(const f16x8*)&Bs[(nrow + i * 16) * 32 + q8];
        }
#pragma unroll
        for (int i = 0; i < 4; ++i)
#pragma unroll
            for (int j = 0; j < 4; ++j)
                acc[i][j] = __builtin_amdgcn_mfma_f32_16x16x32_f16(
                    af[i], bfr[j], acc[i][j], 0, 0, 0);
        __syncthreads();
    }

    // epilogue: C/D layout row=(lane>>4)*4+reg, col=lane&15 (m89-verified)
    // 1) bias+relu, pack fp16 into padded LDS tile  2) coalesced 16B stores
    int col0 = wn * 64 + (l & 15);
    int rloc = wm * 64 + (l >> 4) * 4;
    float bsv[4];
#pragma unroll
    for (int j = 0; j < 4; ++j) bsv[j] = bias[bn + col0 + j * 16];
#pragma unroll
    for (int i = 0; i < 4; ++i)
#pragma unroll
        for (int j = 0; j < 4; ++j)
#pragma unroll
            for (int r = 0; r < 4; ++r) {
                float v = acc[i][j][r] + bsv[j];
                if (relu) v = fmaxf(v, 0.f);
                Cs[(rloc + i * 16 + r) * LDC + col0 + j * 16] = (f16)v;
            }
    __syncthreads();
    int c8 = (tid & 15) * 8;
    int r0 = tid >> 4;
#pragma unroll
    for (int it = 0; it < 8; ++it) {
        int row = r0 + it * 16;
        f16x8 val = *(const f16x8*)&Cs[row * LDC + c8];
        *(f16x8*)&C[(size_t)(bm + row) * DIMN + bn + c8] = val;
    }
}

// ---- residual + layernorm (mode 0) or final residual fp32 out (mode 1) ----
__global__ void res_ln_kernel(const f16* __restrict__ y, f16* __restrict__ h,
                              const float* __restrict__ g, const float* __restrict__ b,
                              float* __restrict__ outF, int mode) {
    int row = blockIdx.x;
    int tid = threadIdx.x;
    int c0 = tid * 4;
    const f16* yr = y + (size_t)row * DIMN;
    f16* hr = h + (size_t)row * DIMN;

    f16x4 yv = *(const f16x4*)&yr[c0];
    f16x4 hv = *(const f16x4*)&hr[c0];
    float v[4];
    float s = 0.f, sq = 0.f;
#pragma unroll
    for (int i = 0; i < 4; ++i) {
        v[i] = (float)yv[i] + (float)hv[i];
        s += v[i]; sq += v[i] * v[i];
    }
#pragma unroll
    for (int o = 32; o > 0; o >>= 1) {
        s += __shfl_xor(s, o);
        sq += __shfl_xor(sq, o);
    }
    __shared__ float red[8];
    int wv = tid >> 6, ln = tid & 63;
    if (ln == 0) { red[wv] = s; red[4 + wv] = sq; }
    __syncthreads();
    float S1 = red[0] + red[1] + red[2] + red[3];
    float S2 = red[4] + red[5] + red[6] + red[7];
    float mu = S1 * (1.f / 1024.f);
    float var = S2 * (1.f / 1024.f) - mu * mu;
    float rs = rsqrtf(var + 1e-5f);

    if (mode == 0) {
        float4 gv = *(const float4*)&g[c0];
        float4 bv = *(const float4*)&b[c0];
        f16x4 outv;
        outv[0] = (f16)((v[0] - mu) * rs * gv.x + bv.x);
        outv[1] = (f16)((v[1] - mu) * rs * gv.y + bv.y);
        outv[2] = (f16)((v[2] - mu) * rs * gv.z + bv.z);
        outv[3] = (f16)((v[3] - mu) * rs * gv.w + bv.w);
        *(f16x4*)&hr[c0] = outv;
    } else {
        float4 ov;
        ov.x = v[0]; ov.y = v[1]; ov.z = v[2]; ov.w = v[3];
        *(float4*)&outF[(size_t)row * DIMN + c0] = ov;
    }
}

extern "C" void kernel_launch(void* const* d_in, const int* in_sizes, int n_in,
                              void* d_out, int out_size, void* d_ws, size_t ws_size,
                              hipStream_t stream) {
    const float* x    = (const float*)d_in[0];
    const int*   qw   = (const int*)d_in[1];
    const float* sc   = (const float*)d_in[2];
    const float* bias = (const float*)d_in[3];
    const float* la   = (const float*)d_in[4];
    const float* lb   = (const float*)d_in[5];
    const float* lng  = (const float*)d_in[6];
    const float* lnb  = (const float*)d_in[7];
    float* out = (float*)d_out;

    char* ws = (char*)d_ws;
    f16* Weff = (f16*)ws;                                   // 37,748,736 B
    f16* H    = (f16*)(ws + (size_t)37748736);              // 67,108,864 B
    f16* P    = (f16*)(ws + (size_t)37748736 + 67108864);   // 67,108,864 B
    f16* Q    = (f16*)d_out;                                // scratch alias (dead before final fp32 write)

    cvt_kernel<<<BATCH * DIMN / (256 * 4), 256, 0, stream>>>(x, H);
    prep_w_kernel<<<NLAYERS * 128, 256, 0, stream>>>(qw, sc, la, lb, Weff);

    for (int blk = 0; blk < NBLOCKS; ++blk) {
        for (int j = 0; j < 3; ++j) {
            int li = blk * 3 + j;
            const f16* in = (j == 0) ? H : ((j == 1) ? P : Q);
            f16* o = (j == 1) ? Q : P;
            gemm_kernel<<<2048, 256, 0, stream>>>(
                in, Weff + ((size_t)li << 20), bias + li * 1024, o, (j < 2) ? 1 : 0);
        }
        int lnidx = (blk < 5) ? blk : 4;  // unused in mode 1
        res_ln_kernel<<<BATCH, 256, 0, stream>>>(
            P, H, lng + lnidx * 1024, lnb + lnidx * 1024, out, (blk == 5) ? 1 : 0);
    }
}